// Round 1
// baseline (781.577 us; speedup 1.0000x reference)
//
#include <hip/hip_runtime.h>
#include <math.h>

// TopKGating: logits = x @ W^T + b  -> softmax(8) -> top-2 (indices, values)
// x: [131072, 1024] f32, W: [8, 1024] f32, b: [8] f32
// out: [N*2] indices (as float) then [N*2] values, flat concat.

#define NUM_TOKENS 131072
#define DIM        1024
#define NE         8
#define TPB        256   // threads per block == tokens per block
#define DC         64    // d-chunk staged per iteration
#define ROWSTRIDE  68    // LDS row stride in floats (64 + 4 pad; 16B-aligned, odd in 16B units)

__global__ __launch_bounds__(TPB)
void topk_gating_kernel(const float* __restrict__ x,
                        const float* __restrict__ W,
                        const float* __restrict__ b,
                        float* __restrict__ out)
{
    __shared__ float lds[TPB * ROWSTRIDE];
    const int t    = threadIdx.x;
    const int tok0 = blockIdx.x * TPB;

    float acc[NE];
#pragma unroll
    for (int e = 0; e < NE; ++e) acc[e] = 0.f;

    const float4* x4   = (const float4*)x;   // [N, 256]
    const float4* W4   = (const float4*)W;   // [8, 256]
    float4*       lds4 = (float4*)lds;       // row stride 17 float4s

    for (int c = 0; c < DIM / DC; ++c) {
        __syncthreads();  // previous chunk's readers done before overwrite
        // Stage [256 tokens x 64 d] tile, coalesced: 16 float4 per thread.
#pragma unroll
        for (int l = 0; l < 16; ++l) {
            int flat = l * TPB + t;
            int r    = flat >> 4;    // token row within block
            int c4   = flat & 15;    // float4 col within chunk
            float4 v = x4[(tok0 + r) * (DIM / 4) + c * (DC / 4) + c4];
            lds4[r * (ROWSTRIDE / 4) + c4] = v;
        }
        __syncthreads();
        // Each thread: its own token's row from LDS, W via uniform (scalar) loads.
#pragma unroll 4
        for (int j = 0; j < DC / 4; ++j) {
            float4 xv = lds4[t * (ROWSTRIDE / 4) + j];
            int d = c * (DC / 4) + j;  // uniform across the wave
#pragma unroll
            for (int e = 0; e < NE; ++e) {
                float4 w = W4[e * (DIM / 4) + d];
                acc[e] = fmaf(xv.x, w.x, acc[e]);
                acc[e] = fmaf(xv.y, w.y, acc[e]);
                acc[e] = fmaf(xv.z, w.z, acc[e]);
                acc[e] = fmaf(xv.w, w.w, acc[e]);
            }
        }
    }

    // Epilogue: bias, stable top-2 on logits (ties -> lower index first, matches lax.top_k)
    float logit[NE];
#pragma unroll
    for (int e = 0; e < NE; ++e) logit[e] = acc[e] + b[e];

    float v1 = -INFINITY, v2 = -INFINITY;
    int   i1 = 0,         i2 = 0;
#pragma unroll
    for (int e = 0; e < NE; ++e) {
        float v = logit[e];
        if (v > v1)      { v2 = v1; i2 = i1; v1 = v; i1 = e; }
        else if (v > v2) { v2 = v;  i2 = e; }
    }

    float sum = 0.f;
#pragma unroll
    for (int e = 0; e < NE; ++e) sum += __expf(logit[e] - v1);
    float inv = 1.0f / sum;
    float p1  = inv;                       // exp(v1 - v1) * inv
    float p2  = __expf(v2 - v1) * inv;

    int n = tok0 + t;
    float2* outi = (float2*)out;                           // indices (as float)
    float2* outv = (float2*)(out + 2 * (size_t)NUM_TOKENS); // values
    outi[n] = make_float2((float)i1, (float)i2);
    outv[n] = make_float2(p1, p2);
}

extern "C" void kernel_launch(void* const* d_in, const int* in_sizes, int n_in,
                              void* d_out, int out_size, void* d_ws, size_t ws_size,
                              hipStream_t stream) {
    const float* x = (const float*)d_in[0];
    const float* W = (const float*)d_in[1];
    const float* b = (const float*)d_in[2];
    float* out = (float*)d_out;

    dim3 grid(NUM_TOKENS / TPB);  // 512 blocks
    dim3 block(TPB);
    topk_gating_kernel<<<grid, block, 0, stream>>>(x, W, b, out);
}